// Round 17
// baseline (60.840 us; speedup 1.0000x reference)
//
#include <hip/hip_runtime.h>
#include <cstddef>
#include <cmath>

#define BN 2
#define CH 48
#define HW 4096
#define NH 3
#define QC 144      // 3*CH
#define RR 3        // CH/16
#define KSPLIT 4
#define NPLANE 17   // 16 acc + 1 denom planes per (ks,bh)
#define LOG2E 1.4426950408889634f

typedef __attribute__((ext_vector_type(8))) short bf16x8;
typedef __attribute__((ext_vector_type(16))) float f32x16;
typedef __attribute__((ext_vector_type(4))) float f32x4;

// ---- workspace layout (floats) ----
constexpr size_t OFF_BP  = 0;                       // 128*48 rows (b*64+row)
constexpr size_t OFF_QB  = 12288;                   // 98304 (bf16 [bh][n][16])
constexpr size_t OFF_KB  = OFF_QB + 98304;
constexpr size_t OFF_VT  = OFF_KB + 98304;
constexpr size_t OFF_PART= OFF_VT + 98304 + 1179648; // bf16 planes (half size)

static __device__ __forceinline__ unsigned cvtpk(float lo, float hi) {
  unsigned r;
  asm("v_cvt_pk_bf16_f32 %0, %1, %2" : "=v"(r) : "v"(lo), "v"(hi));
  return r;
}

static __device__ __forceinline__ float bf2f(ushort u) {
  return __uint_as_float((unsigned)u << 16);
}

static __device__ __forceinline__ float fexp2(float x) {
#if __has_builtin(__builtin_amdgcn_exp2f)
  return __builtin_amdgcn_exp2f(x);
#else
  float r; asm("v_exp_f32 %0, %1" : "=v"(r) : "v"(x)); return r;
#endif
}

// ---------- K1: fused LN1 + conv1x1 + depthwise3x3 + token norm/pack ----------
// R13 LN structure (proven conflict-free), but conv units re-assigned so each
// wave computes exactly the 6 channels its dw-stencil needs -> conv results in
// REGISTERS qtr[6][3]; horizontal halo via __shfl. qt LDS (36KB) deleted;
// xt1 double-buffered; barriers 10 -> 6. Weights all readfirstlane -> s_load.
__global__ __launch_bounds__(512) void k_front(const float* __restrict__ x,
                                               const float* __restrict__ lw,
                                               const float* __restrict__ lb,
                                               const float* __restrict__ w,
                                               const float* __restrict__ bias,
                                               const float* __restrict__ dww,
                                               const float* __restrict__ dwb,
                                               const float* __restrict__ temp,
                                               ushort* __restrict__ Qb,
                                               ushort* __restrict__ Kb,
                                               ushort* __restrict__ Vtb,
                                               float* __restrict__ bpool) {
  __shared__ float xt1[2][CH][64];       // LN output, double-buffered by row
  __shared__ float red1[8][64], red2[8][64];
  int blk = blockIdx.x;                  // bh*64 + row
  int row = blk & 63, bh = blk >> 6;
  int b = bh / NH, h = bh % NH;
  int t = threadIdx.x;
  int px = t & 63, grp = t >> 6;         // grp 0..7 (= wave id)

  float qtr[6][3];                       // [unit][stencil row], unit i = (which=i>>1, j=i&1)
#pragma unroll
  for (int r = 0; r < 3; ++r) {
    int yy = row + r - 1;
    if (yy < 0 || yy >= 64) {            // block-uniform: no barriers inside
#pragma unroll
      for (int i = 0; i < 6; ++i) qtr[i][r] = 0.f;
      continue;
    }
    const int buf = r & 1;
    // LN phase: wave grp loads 6 channels of this row (R13-proven layout)
    const float* xb = x + (size_t)b*CH*HW + yy*64 + px;
    float v[6]; float s = 0.f, ss = 0.f;
#pragma unroll
    for (int j = 0; j < 6; ++j) {
      float vv = xb[(size_t)(grp*6 + j)*HW];
      v[j] = vv; s += vv; ss += vv*vv;
    }
    red1[grp][px] = s; red2[grp][px] = ss;
    __syncthreads();
    float stot = 0.f, sstot = 0.f;
#pragma unroll
    for (int i = 0; i < 8; ++i) { stot += red1[i][px]; sstot += red2[i][px]; }
    float mu = stot * (1.f/CH);
    float rs = rsqrtf(sstot*(1.f/CH) - mu*mu + 1e-6f);
#pragma unroll
    for (int j = 0; j < 6; ++j) {
      int c = grp*6 + j;
      xt1[buf][c][px] = lw[c]*((v[j]-mu)*rs) + lb[c];
    }
    __syncthreads();
    // per-row pool partial (h==0 blocks, center row only; buf==1 for r==1)
    if (r == 1 && h == 0 && t < CH) {
      float a = 0.f;
#pragma unroll
      for (int p2 = 0; p2 < 64; ++p2) a += xt1[1][t][p2];
      bpool[(size_t)(b*64 + row)*CH + t] = a;
    }
    // conv phase: wave grp computes ITS OWN dw channels (which*16 + grp*2 + j)
    float xv[CH];
#pragma unroll
    for (int ci = 0; ci < CH; ++ci) xv[ci] = xt1[buf][ci][px];
#pragma unroll
    for (int i = 0; i < 6; ++i) {
      int which = i >> 1, j = i & 1;
      int c = __builtin_amdgcn_readfirstlane(which*48 + h*16 + grp*2 + j);
      const float* wrow = w + (size_t)c*CH;
      float a = bias[c];
#pragma unroll
      for (int ci = 0; ci < CH; ++ci) a += wrow[ci]*xv[ci];
      qtr[i][r] = a;
    }
    // no end-of-row barrier: next row writes buf^1; row r+2's write to buf is
    // ordered after two intervening barriers.
  }

  // depthwise 3x3: vertical in registers, horizontal via lane shuffles
  int n = row*64 + px;
  float q[2], k[2], vv2[2];
  float sq = 0.f, sk = 0.f;
#pragma unroll
  for (int i = 0; i < 6; ++i) {
    int which = i >> 1, j = i & 1, cc = grp*2 + j;
    int cg = __builtin_amdgcn_readfirstlane(which*48 + h*16 + cc);
    const float* wc = dww + (size_t)cg*9;
    float w0 = wc[0], w1 = wc[1], w2 = wc[2],
          w3 = wc[3], w4 = wc[4], w5 = wc[5],
          w6 = wc[6], w7 = wc[7], w8 = wc[8];
    float a = dwb[cg];
#pragma unroll
    for (int rr = 0; rr < 3; ++rr) {
      float wl = rr==0?w0:(rr==1?w3:w6);
      float wm = rr==0?w1:(rr==1?w4:w7);
      float wr = rr==0?w2:(rr==1?w5:w8);
      float tm = qtr[i][rr];
      float tl = __shfl(tm, px - 1); tl = (px >= 1)  ? tl : 0.f;
      float tr = __shfl(tm, px + 1); tr = (px <= 62) ? tr : 0.f;
      a += wl*tl + wm*tm + wr*tr;
    }
    if (which == 0)      { q[j] = a;  sq += a*a; }
    else if (which == 1) { k[j] = a;  sk += a*a; }
    else                 vv2[j] = a;
  }
  red1[grp][px] = sq; red2[grp][px] = sk;
  __syncthreads();
  float tsq = 0.f, tsk = 0.f;
#pragma unroll
  for (int i = 0; i < 8; ++i) { tsq += red1[i][px]; tsk += red2[i][px]; }
  float tq = temp[h] * LOG2E / fmaxf(sqrtf(tsq), 1e-12f);
  float ik = 1.f            / fmaxf(sqrtf(tsk), 1e-12f);
  *(uint*)(Qb + ((size_t)bh*HW + n)*16 + grp*2) = cvtpk(q[0]*tq, q[1]*tq);
  *(uint*)(Kb + ((size_t)bh*HW + n)*16 + grp*2) = cvtpk(k[0]*ik, k[1]*ik);
  Vtb[((size_t)bh*16 + grp*2    )*HW + n] = (ushort)(cvtpk(vv2[0], vv2[0]) & 0xffffu);
  Vtb[((size_t)bh*16 + grp*2 + 1)*HW + n] = (ushort)(cvtpk(vv2[1], vv2[1]) & 0xffffu);
}

// ---------- K2: MFMA flash attention (R13) + bf16 part output ----------
#define PACK(stv, wbp) do {                                              \
  _Pragma("unroll")                                                      \
  for (int g4 = 0; g4 < 4; ++g4) {                                       \
    float e0 = fmaxf(fexp2((stv)[4*g4+0]), 1.f);                         \
    float e1 = fmaxf(fexp2((stv)[4*g4+1]), 1.f);                         \
    float e2 = fmaxf(fexp2((stv)[4*g4+2]), 1.f);                         \
    float e3 = fmaxf(fexp2((stv)[4*g4+3]), 1.f);                         \
    uint2 pk;                                                            \
    pk.x = cvtpk(e0, e1);                                                \
    pk.y = cvtpk(e2, e3);                                                \
    *(uint2*)((wbp) + wroff + 16*(g4 ^ sw)) = pk;                        \
  } } while (0)

__global__ __launch_bounds__(256) void k_attn(const ushort* __restrict__ Qb,
                                              const ushort* __restrict__ Kb,
                                              const ushort* __restrict__ Vtb,
                                              ushort* __restrict__ part) {
  __shared__ char smem[4][4096];       // per-wave slice
  int blk = blockIdx.x;                // bh(6) x qt(32) x ks(4)
  int ks = blk & (KSPLIT-1);
  int qt = (blk >> 2) & 31;
  int bh = blk >> 7;
  int lane = threadIdx.x & 63;
  int wid  = threadIdx.x >> 6;
  int l31 = lane & 31;
  int lhi = lane >> 5;
  int qbase = qt*128 + wid*32;

  bf16x8 qf = *(const bf16x8*)(Qb + ((size_t)bh*HW + qbase + l31)*16 + lhi*8);

  const f32x16 z16 = {0,0,0,0,0,0,0,0,0,0,0,0,0,0,0,0};
  const short oneb = (short)0x3f80;
  const bf16x8 ones = {oneb,oneb,oneb,oneb,oneb,oneb,oneb,oneb};
  f32x4 acc0 = {0,0,0,0}, acc1 = {0,0,0,0};
  f32x4 accD0 = {0,0,0,0}, accD1 = {0,0,0,0};
  char* base = &smem[wid][0];
  int qr = lane & 15, gr = lane >> 4;
  int rdoff0 = qr*64 + 16*(gr ^ ((qr>>1)&3));
  int sw = (l31 >> 1) & 3;
  int wroff = l31*64 + 8*lhi;

  const ushort* Kbase = Kb + (size_t)bh*HW*16;
  const ushort* Vbase = Vtb + ((size_t)bh*16 + qr)*HW;
  int kbeg = ks * (HW/KSPLIT);
  constexpr int ITERS = (HW/KSPLIT)/32;   // 32

  // prologue: S(0) -> buf0; prefetch K(1) and V(0)
  bf16x8 kf = *(const bf16x8*)(Kbase + (size_t)(kbeg + l31)*16 + lhi*8);
  f32x16 st = __builtin_amdgcn_mfma_f32_32x32x16_bf16(kf, qf, z16, 0, 0, 0);
  bf16x8 kfn = *(const bf16x8*)(Kbase + (size_t)(kbeg + 32 + l31)*16 + lhi*8);
  bf16x8 vfn = *(const bf16x8*)(Vbase + kbeg + 8*gr);
  PACK(st, base);

#pragma unroll 4
  for (int i = 1; i < ITERS; ++i) {
    char* rb = base + ((i-1) & 1)*2048;
    bf16x8 pa0 = *(const bf16x8*)(rb + rdoff0);
    bf16x8 pa1 = *(const bf16x8*)(rb + 1024 + rdoff0);
    __builtin_amdgcn_s_setprio(1);
    f32x16 stn = __builtin_amdgcn_mfma_f32_32x32x16_bf16(kfn, qf, z16, 0, 0, 0);
    // prefetch K(i+1); at i=ITERS-1 reads adjacent ws region, never consumed.
    kfn = *(const bf16x8*)(Kbase + (size_t)(kbeg + (i+1)*32 + l31)*16 + lhi*8);
    bf16x8 vf = vfn;
    vfn = *(const bf16x8*)(Vbase + kbeg + i*32 + 8*gr);   // V(i) for next iter
    acc0  = __builtin_amdgcn_mfma_f32_16x16x32_bf16(pa0, vf, acc0, 0, 0, 0);
    acc1  = __builtin_amdgcn_mfma_f32_16x16x32_bf16(pa1, vf, acc1, 0, 0, 0);
    accD0 = __builtin_amdgcn_mfma_f32_16x16x32_bf16(pa0, ones, accD0, 0, 0, 0);
    accD1 = __builtin_amdgcn_mfma_f32_16x16x32_bf16(pa1, ones, accD1, 0, 0, 0);
    __builtin_amdgcn_s_setprio(0);
    PACK(stn, base + (i & 1)*2048);
  }
  {
    char* rb = base + ((ITERS-1) & 1)*2048;
    bf16x8 pa0 = *(const bf16x8*)(rb + rdoff0);
    bf16x8 pa1 = *(const bf16x8*)(rb + 1024 + rdoff0);
    acc0  = __builtin_amdgcn_mfma_f32_16x16x32_bf16(pa0, vfn, acc0, 0, 0, 0);
    acc1  = __builtin_amdgcn_mfma_f32_16x16x32_bf16(pa1, vfn, acc1, 0, 0, 0);
    accD0 = __builtin_amdgcn_mfma_f32_16x16x32_bf16(pa0, ones, accD0, 0, 0, 0);
    accD1 = __builtin_amdgcn_mfma_f32_16x16x32_bf16(pa1, ones, accD1, 0, 0, 0);
  }

  // epilogue overlay: ep[slot][q] f32 in the wave's own slice
  float* ep = (float*)base;
#pragma unroll
  for (int r = 0; r < 4; ++r) {
    ep[qr*32 + gr*4 + r]      = acc0[r];
    ep[qr*32 + gr*4 + 16 + r] = acc1[r];
  }
  if (qr == 0) {
#pragma unroll
    for (int r = 0; r < 4; ++r) {
      ep[16*32 + gr*4 + r]      = accD0[r];
      ep[16*32 + gr*4 + 16 + r] = accD1[r];
    }
  }
  __syncthreads();
  size_t pb = ((size_t)(ks*6 + bh))*NPLANE;
  for (int i = threadIdx.x; i < 4*32*NPLANE; i += 256) {
    int w = i / (32*NPLANE);
    int rem = i - w*(32*NPLANE);
    int cc = rem >> 5;
    int q = rem & 31;
    float v = ((float*)&smem[w][0])[cc*32 + q];
    part[(pb + cc)*HW + qt*128 + w*32 + q] = (ushort)(cvtpk(v, v) & 0xffffu);
  }
}

// ---------- K3: tail — SE + ksplit-reduce + combine + LN2 + full FFN ----------
// 128 blocks x 768 thr (12 waves); wave w owns 4 WAVE-UNIFORM channels.
__global__ __launch_bounds__(768) void k_tail(const ushort* __restrict__ part,
                                              const float* __restrict__ x,
                                              const float* __restrict__ lw1,
                                              const float* __restrict__ lb1,
                                              const float* __restrict__ bpool,
                                              const float* __restrict__ w1,
                                              const float* __restrict__ b1,
                                              const float* __restrict__ w2,
                                              const float* __restrict__ b2,
                                              const float* __restrict__ beta,
                                              const float* __restrict__ beta2,
                                              const float* __restrict__ lw2,
                                              const float* __restrict__ lb2,
                                              const float* __restrict__ w4,
                                              const float* __restrict__ b4,
                                              const float* __restrict__ w5,
                                              const float* __restrict__ b5,
                                              const float* __restrict__ gamma,
                                              float* __restrict__ out) {
  __shared__ float sepm[CH][4];
  __shared__ float pmL[CH];
  __shared__ float yrL[4];
  __shared__ float seL[CH];
  __shared__ float r1[12][64], r2[12][64], r3[12][64], r4[12][64];
  __shared__ float xt[CH][65];   // LN2 output
  __shared__ float gt[CH][65];   // gate output
  int t = threadIdx.x;
  int px = t & 63, w = t >> 6;        // 12 waves
  int h = w >> 2;
  int c0 = __builtin_amdgcn_readfirstlane(w * 4);
  int qoff = __builtin_amdgcn_readfirstlane((w & 3) * 4);
  int gp = blockIdx.x*64 + px;
  int b = gp >> 12, n = gp & 4095;
  int bh = b*NH + h;

  // SE MLP (block-redundant; bpool is L2-hot; 64 row-partials per b)
  if (t < 192) {
    int c = t % CH, j = t / CH;       // j 0..3
    const float* bp = bpool + (size_t)(b*64 + j*16)*CH + c;
    float a = 0.f;
#pragma unroll
    for (int i = 0; i < 16; ++i) a += bp[(size_t)i*CH];
    sepm[c][j] = a;
  }
  __syncthreads();
  if (t < CH) pmL[t] = (sepm[t][0]+sepm[t][1]+sepm[t][2]+sepm[t][3]) * (1.f/HW);
  __syncthreads();
  if (t < RR) {
    float a = b1[t];
    for (int c = 0; c < CH; ++c) a += w1[t*CH+c]*pmL[c];
    yrL[t] = fmaxf(a, 0.f);
  }
  __syncthreads();
  if (t < CH) {
    float a = b2[t];
    for (int r = 0; r < RR; ++r) a += w2[t*RR+r]*yrL[r];
    seL[t] = 1.f/(1.f+__expf(-a));
  }

  // ksplit reduce: 4 channels + den per thread (bf16 part planes)
  float acc[4] = {0,0,0,0};
  float den = 0.f;
#pragma unroll
  for (int ks = 0; ks < KSPLIT; ++ks) {
    const ushort* pl = part + ((size_t)((ks*6+bh)*NPLANE + qoff))*HW + n;
#pragma unroll
    for (int cc = 0; cc < 4; ++cc) acc[cc] += bf2f(pl[(size_t)cc*HW]);
    den += bf2f(pl[(size_t)(16 - qoff)*HW]);
  }
  // LN1 stats on x
  const float* xp = x + ((size_t)b*CH + c0)*HW + n;
  float xv[4]; float s = 0.f, ssum = 0.f;
#pragma unroll
  for (int cc = 0; cc < 4; ++cc) {
    float vv = xp[(size_t)cc*HW];
    xv[cc] = vv; s += vv; ssum += vv*vv;
  }
  r1[w][px] = s; r2[w][px] = ssum;
  __syncthreads();
  float stot = 0.f, sstot = 0.f;
#pragma unroll
  for (int i = 0; i < 12; ++i) { stot += r1[i][px]; sstot += r2[i][px]; }
  float mu = stot*(1.f/CH);
  float rs = rsqrtf(sstot*(1.f/CH) - mu*mu + 1e-6f);
  float inv = 1.f / den;
  float yv[4]; float s2 = 0.f, ss2 = 0.f;
#pragma unroll
  for (int cc = 0; cc < 4; ++cc) {
    int c = c0 + cc;
    float xnv = lw1[c]*((xv[cc]-mu)*rs) + lb1[c];
    float y = xv[cc] + xnv*seL[c]*beta[c] + acc[cc]*inv*beta2[c];
    yv[cc] = y; s2 += y; ss2 += y*y;
  }
  r3[w][px] = s2; r4[w][px] = ss2;
  __syncthreads();
  float s2t = 0.f, ss2t = 0.f;
#pragma unroll
  for (int i = 0; i < 12; ++i) { s2t += r3[i][px]; ss2t += r4[i][px]; }
  float mu2 = s2t*(1.f/CH);
  float rs2 = rsqrtf(ss2t*(1.f/CH) - mu2*mu2 + 1e-6f);
#pragma unroll
  for (int cc = 0; cc < 4; ++cc) {
    int c = c0 + cc;
    xt[c][px] = lw2[c]*((yv[cc]-mu2)*rs2) + lb2[c];
  }
  __syncthreads();

  // conv4 + gate: wave-uniform rows via s_load
  float f1[4], f2[4];
#pragma unroll
  for (int j = 0; j < 4; ++j) { f1[j] = b4[c0+j]; f2[j] = b4[CH+c0+j]; }
#pragma unroll 8
  for (int c = 0; c < CH; ++c) {
    float tc = xt[c][px];
#pragma unroll
    for (int j = 0; j < 4; ++j) {
      f1[j] += w4[(size_t)(c0+j)*CH + c] * tc;
      f2[j] += w4[(size_t)(CH+c0+j)*CH + c] * tc;
    }
  }
#pragma unroll
  for (int j = 0; j < 4; ++j) gt[c0+j][px] = f1[j]*f2[j];
  __syncthreads();

  // conv5 + residual
  float f5[4];
#pragma unroll
  for (int j = 0; j < 4; ++j) f5[j] = b5[c0+j];
#pragma unroll 8
  for (int c = 0; c < CH; ++c) {
    float gc = gt[c][px];
#pragma unroll
    for (int j = 0; j < 4; ++j) f5[j] += w5[(size_t)(c0+j)*CH + c] * gc;
  }
  float* op = out + ((size_t)b*CH + c0)*HW + n;
#pragma unroll
  for (int j = 0; j < 4; ++j)
    op[(size_t)j*HW] = yv[j] + f5[j]*gamma[c0+j];
}

extern "C" void kernel_launch(void* const* d_in, const int* in_sizes, int n_in,
                              void* d_out, int out_size, void* d_ws, size_t ws_size,
                              hipStream_t stream) {
  const float* x      = (const float*)d_in[0];
  const float* ln1_w  = (const float*)d_in[1];
  const float* ln1_b  = (const float*)d_in[2];
  const float* qkv_w  = (const float*)d_in[3];
  const float* qkv_b  = (const float*)d_in[4];
  const float* dw_w   = (const float*)d_in[5];
  const float* dw_b   = (const float*)d_in[6];
  const float* temp   = (const float*)d_in[7];
  const float* ca_w1  = (const float*)d_in[8];
  const float* ca_b1  = (const float*)d_in[9];
  const float* ca_w2  = (const float*)d_in[10];
  const float* ca_b2  = (const float*)d_in[11];
  const float* beta   = (const float*)d_in[12];
  const float* beta2  = (const float*)d_in[13];
  const float* ln2_w  = (const float*)d_in[14];
  const float* ln2_b  = (const float*)d_in[15];
  const float* conv4_w= (const float*)d_in[16];
  const float* conv4_b= (const float*)d_in[17];
  const float* conv5_w= (const float*)d_in[18];
  const float* conv5_b= (const float*)d_in[19];
  const float* gamma  = (const float*)d_in[20];

  float* ws   = (float*)d_ws;
  float* bp   = ws + OFF_BP;
  ushort* Qb  = (ushort*)(ws + OFF_QB);
  ushort* Kb  = (ushort*)(ws + OFF_KB);
  ushort* Vtb = (ushort*)(ws + OFF_VT);
  ushort* part= (ushort*)(ws + OFF_PART);
  float* out  = (float*)d_out;

  k_front<<<384, 512, 0, stream>>>(x, ln1_w, ln1_b, qkv_w, qkv_b,
                                   dw_w, dw_b, temp, Qb, Kb, Vtb, bp);
  k_attn <<<768, 256, 0, stream>>>(Qb, Kb, Vtb, part);
  k_tail <<<128, 768, 0, stream>>>(part, x, ln1_w, ln1_b, bp,
                                   ca_w1, ca_b1, ca_w2, ca_b2,
                                   beta, beta2, ln2_w, ln2_b,
                                   conv4_w, conv4_b, conv5_w, conv5_b,
                                   gamma, out);
}

// Round 18
// 50.958 us; speedup vs baseline: 1.1939x; 1.1939x over previous
//
#include <hip/hip_runtime.h>
#include <cstddef>
#include <cmath>

#define BN 2
#define CH 48
#define HW 4096
#define NH 3
#define QC 144      // 3*CH
#define RR 3        // CH/16
#define KSPLIT 4
#define NPLANE 17   // 16 acc + 1 denom planes per (ks,bh)
#define LOG2E 1.4426950408889634f

typedef __attribute__((ext_vector_type(8))) short bf16x8;
typedef __attribute__((ext_vector_type(16))) float f32x16;
typedef __attribute__((ext_vector_type(4))) float f32x4;

// ---- workspace layout (floats) ----
constexpr size_t OFF_BP  = 0;                       // 128*48 rows (b*64+row)
constexpr size_t OFF_QB  = 12288;                   // 98304 (bf16 [bh][n][16])
constexpr size_t OFF_KB  = OFF_QB + 98304;
constexpr size_t OFF_VT  = OFF_KB + 98304;
constexpr size_t OFF_PART= OFF_VT + 98304 + 1179648; // bf16 planes (half size)

static __device__ __forceinline__ unsigned cvtpk(float lo, float hi) {
  unsigned r;
  asm("v_cvt_pk_bf16_f32 %0, %1, %2" : "=v"(r) : "v"(lo), "v"(hi));
  return r;
}

static __device__ __forceinline__ float bf2f(ushort u) {
  return __uint_as_float((unsigned)u << 16);
}

static __device__ __forceinline__ float fexp2(float x) {
#if __has_builtin(__builtin_amdgcn_exp2f)
  return __builtin_amdgcn_exp2f(x);
#else
  float r; asm("v_exp_f32 %0, %1" : "=v"(r) : "v"(x)); return r;
#endif
}

// ---------- K1: fused LN1 + conv1x1 + depthwise3x3 + token norm/pack ----------
// EXACT R13/R16 structure (proven best): row-loop LN with cross-wave LDS
// reduce, qt[3][CH][64] in LDS, all weight rows readfirstlane'd -> s_load.
__global__ __launch_bounds__(512) void k_front(const float* __restrict__ x,
                                               const float* __restrict__ lw,
                                               const float* __restrict__ lb,
                                               const float* __restrict__ w,
                                               const float* __restrict__ bias,
                                               const float* __restrict__ dww,
                                               const float* __restrict__ dwb,
                                               const float* __restrict__ temp,
                                               ushort* __restrict__ Qb,
                                               ushort* __restrict__ Kb,
                                               ushort* __restrict__ Vtb,
                                               float* __restrict__ bpool) {
  __shared__ float xt1[CH][64];          // LN output, one row at a time
  __shared__ float qt[3][CH][64];        // conv1x1 outputs (oc = which*16+cc)
  __shared__ float red1[8][64], red2[8][64];
  int blk = blockIdx.x;                  // bh*64 + row
  int row = blk & 63, bh = blk >> 6;
  int b = bh / NH, h = bh % NH;
  int t = threadIdx.x;
  int px = t & 63, grp = t >> 6;         // grp 0..7 (= wave id)

  for (int r = 0; r < 3; ++r) {
    int yy = row + r - 1;
    if (yy < 0 || yy >= 64) {            // block-uniform branch
      for (int i = t; i < CH*64; i += 512) (&qt[r][0][0])[i] = 0.f;
      __syncthreads();
      continue;
    }
    // LN phase: wave grp loads 6 channels of this row
    const float* xb = x + (size_t)b*CH*HW + yy*64 + px;
    float v[6]; float s = 0.f, ss = 0.f;
#pragma unroll
    for (int j = 0; j < 6; ++j) {
      float vv = xb[(size_t)(grp*6 + j)*HW];
      v[j] = vv; s += vv; ss += vv*vv;
    }
    red1[grp][px] = s; red2[grp][px] = ss;
    __syncthreads();
    float stot = 0.f, sstot = 0.f;
#pragma unroll
    for (int i = 0; i < 8; ++i) { stot += red1[i][px]; sstot += red2[i][px]; }
    float mu = stot * (1.f/CH);
    float rs = rsqrtf(sstot*(1.f/CH) - mu*mu + 1e-6f);
#pragma unroll
    for (int j = 0; j < 6; ++j) {
      int c = grp*6 + j;
      xt1[c][px] = lw[c]*((v[j]-mu)*rs) + lb[c];
    }
    __syncthreads();
    // per-row pool partial (h==0 blocks, center row only)
    if (r == 1 && h == 0 && t < CH) {
      float a = 0.f;
#pragma unroll
      for (int p2 = 0; p2 < 64; ++p2) a += xt1[t][p2];
      bpool[(size_t)(b*64 + row)*CH + t] = a;
    }
    // conv phase: wave grp computes oc = grp*6..+5 (weights via s_load)
    float xv[CH];
#pragma unroll
    for (int ci = 0; ci < CH; ++ci) xv[ci] = xt1[ci][px];
#pragma unroll
    for (int oi = 0; oi < 6; ++oi) {
      int oc = grp*6 + oi;
      int c = __builtin_amdgcn_readfirstlane((oc >> 4)*48 + h*16 + (oc & 15));
      const float* wrow = w + (size_t)c*CH;
      float a = bias[c];
#pragma unroll
      for (int ci = 0; ci < CH; ++ci) a += wrow[ci]*xv[ci];
      qt[r][oc][px] = a;
    }
    __syncthreads();
  }

  // depthwise 3x3 (rows in LDS) + norms + pack; weights via s_load
  int n = row*64 + px;
  float q[2], k[2], vv2[2];
  float sq = 0.f, sk = 0.f;
#pragma unroll
  for (int j = 0; j < 2; ++j) {
    int cc = grp*2 + j;
#pragma unroll
    for (int which = 0; which < 3; ++which) {
      int oc = which*16 + cc;
      int cg = __builtin_amdgcn_readfirstlane(which*48 + h*16 + cc);
      const float* wc = dww + (size_t)cg*9;
      float w0 = wc[0], w1 = wc[1], w2 = wc[2],
            w3 = wc[3], w4 = wc[4], w5 = wc[5],
            w6 = wc[6], w7 = wc[7], w8 = wc[8];
      float a = dwb[cg];
#pragma unroll
      for (int rr = 0; rr < 3; ++rr) {
        float wl = rr==0?w0:(rr==1?w3:w6);
        float wm = rr==0?w1:(rr==1?w4:w7);
        float wr = rr==0?w2:(rr==1?w5:w8);
        float tm = qt[rr][oc][px];
        float tl = (px >= 1)  ? qt[rr][oc][px-1] : 0.f;
        float tr = (px <= 62) ? qt[rr][oc][px+1] : 0.f;
        a += wl*tl + wm*tm + wr*tr;
      }
      if (which == 0)      { q[j] = a;  sq += a*a; }
      else if (which == 1) { k[j] = a;  sk += a*a; }
      else                 vv2[j] = a;
    }
  }
  red1[grp][px] = sq; red2[grp][px] = sk;
  __syncthreads();
  float tsq = 0.f, tsk = 0.f;
#pragma unroll
  for (int i = 0; i < 8; ++i) { tsq += red1[i][px]; tsk += red2[i][px]; }
  float tq = temp[h] * LOG2E / fmaxf(sqrtf(tsq), 1e-12f);
  float ik = 1.f            / fmaxf(sqrtf(tsk), 1e-12f);
  *(uint*)(Qb + ((size_t)bh*HW + n)*16 + grp*2) = cvtpk(q[0]*tq, q[1]*tq);
  *(uint*)(Kb + ((size_t)bh*HW + n)*16 + grp*2) = cvtpk(k[0]*ik, k[1]*ik);
  Vtb[((size_t)bh*16 + grp*2    )*HW + n] = (ushort)(cvtpk(vv2[0], vv2[0]) & 0xffffu);
  Vtb[((size_t)bh*16 + grp*2 + 1)*HW + n] = (ushort)(cvtpk(vv2[1], vv2[1]) & 0xffffu);
}

// ---------- K2: MFMA flash attention (R16) + full unroll ----------
#define PACK(stv, wbp) do {                                              \
  _Pragma("unroll")                                                      \
  for (int g4 = 0; g4 < 4; ++g4) {                                       \
    float e0 = fmaxf(fexp2((stv)[4*g4+0]), 1.f);                         \
    float e1 = fmaxf(fexp2((stv)[4*g4+1]), 1.f);                         \
    float e2 = fmaxf(fexp2((stv)[4*g4+2]), 1.f);                         \
    float e3 = fmaxf(fexp2((stv)[4*g4+3]), 1.f);                         \
    uint2 pk;                                                            \
    pk.x = cvtpk(e0, e1);                                                \
    pk.y = cvtpk(e2, e3);                                                \
    *(uint2*)((wbp) + wroff + 16*(g4 ^ sw)) = pk;                        \
  } } while (0)

__global__ __launch_bounds__(256) void k_attn(const ushort* __restrict__ Qb,
                                              const ushort* __restrict__ Kb,
                                              const ushort* __restrict__ Vtb,
                                              ushort* __restrict__ part) {
  __shared__ char smem[4][4096];       // per-wave slice
  int blk = blockIdx.x;                // bh(6) x qt(32) x ks(4)
  int ks = blk & (KSPLIT-1);
  int qt = (blk >> 2) & 31;
  int bh = blk >> 7;
  int lane = threadIdx.x & 63;
  int wid  = threadIdx.x >> 6;
  int l31 = lane & 31;
  int lhi = lane >> 5;
  int qbase = qt*128 + wid*32;

  bf16x8 qf = *(const bf16x8*)(Qb + ((size_t)bh*HW + qbase + l31)*16 + lhi*8);

  const f32x16 z16 = {0,0,0,0,0,0,0,0,0,0,0,0,0,0,0,0};
  const short oneb = (short)0x3f80;
  const bf16x8 ones = {oneb,oneb,oneb,oneb,oneb,oneb,oneb,oneb};
  f32x4 acc0 = {0,0,0,0}, acc1 = {0,0,0,0};
  f32x4 accD0 = {0,0,0,0}, accD1 = {0,0,0,0};
  char* base = &smem[wid][0];
  int qr = lane & 15, gr = lane >> 4;
  int rdoff0 = qr*64 + 16*(gr ^ ((qr>>1)&3));
  int sw = (l31 >> 1) & 3;
  int wroff = l31*64 + 8*lhi;

  const ushort* Kbase = Kb + (size_t)bh*HW*16;
  const ushort* Vbase = Vtb + ((size_t)bh*16 + qr)*HW;
  int kbeg = ks * (HW/KSPLIT);
  constexpr int ITERS = (HW/KSPLIT)/32;   // 32

  // prologue: S(0) -> buf0; prefetch K(1) and V(0)
  bf16x8 kf = *(const bf16x8*)(Kbase + (size_t)(kbeg + l31)*16 + lhi*8);
  f32x16 st = __builtin_amdgcn_mfma_f32_32x32x16_bf16(kf, qf, z16, 0, 0, 0);
  bf16x8 kfn = *(const bf16x8*)(Kbase + (size_t)(kbeg + 32 + l31)*16 + lhi*8);
  bf16x8 vfn = *(const bf16x8*)(Vbase + kbeg + 8*gr);
  PACK(st, base);

#pragma unroll
  for (int i = 1; i < ITERS; ++i) {
    char* rb = base + ((i-1) & 1)*2048;
    bf16x8 pa0 = *(const bf16x8*)(rb + rdoff0);
    bf16x8 pa1 = *(const bf16x8*)(rb + 1024 + rdoff0);
    __builtin_amdgcn_s_setprio(1);
    f32x16 stn = __builtin_amdgcn_mfma_f32_32x32x16_bf16(kfn, qf, z16, 0, 0, 0);
    // prefetch K(i+1); at i=ITERS-1 reads adjacent ws region, never consumed.
    kfn = *(const bf16x8*)(Kbase + (size_t)(kbeg + (i+1)*32 + l31)*16 + lhi*8);
    bf16x8 vf = vfn;
    vfn = *(const bf16x8*)(Vbase + kbeg + i*32 + 8*gr);   // V(i) for next iter
    acc0  = __builtin_amdgcn_mfma_f32_16x16x32_bf16(pa0, vf, acc0, 0, 0, 0);
    acc1  = __builtin_amdgcn_mfma_f32_16x16x32_bf16(pa1, vf, acc1, 0, 0, 0);
    accD0 = __builtin_amdgcn_mfma_f32_16x16x32_bf16(pa0, ones, accD0, 0, 0, 0);
    accD1 = __builtin_amdgcn_mfma_f32_16x16x32_bf16(pa1, ones, accD1, 0, 0, 0);
    __builtin_amdgcn_s_setprio(0);
    PACK(stn, base + (i & 1)*2048);
  }
  {
    char* rb = base + ((ITERS-1) & 1)*2048;
    bf16x8 pa0 = *(const bf16x8*)(rb + rdoff0);
    bf16x8 pa1 = *(const bf16x8*)(rb + 1024 + rdoff0);
    acc0  = __builtin_amdgcn_mfma_f32_16x16x32_bf16(pa0, vfn, acc0, 0, 0, 0);
    acc1  = __builtin_amdgcn_mfma_f32_16x16x32_bf16(pa1, vfn, acc1, 0, 0, 0);
    accD0 = __builtin_amdgcn_mfma_f32_16x16x32_bf16(pa0, ones, accD0, 0, 0, 0);
    accD1 = __builtin_amdgcn_mfma_f32_16x16x32_bf16(pa1, ones, accD1, 0, 0, 0);
  }

  // epilogue overlay: ep[slot][q] f32 in the wave's own slice
  float* ep = (float*)base;
#pragma unroll
  for (int r = 0; r < 4; ++r) {
    ep[qr*32 + gr*4 + r]      = acc0[r];
    ep[qr*32 + gr*4 + 16 + r] = acc1[r];
  }
  if (qr == 0) {
#pragma unroll
    for (int r = 0; r < 4; ++r) {
      ep[16*32 + gr*4 + r]      = accD0[r];
      ep[16*32 + gr*4 + 16 + r] = accD1[r];
    }
  }
  __syncthreads();
  size_t pb = ((size_t)(ks*6 + bh))*NPLANE;
  for (int i = threadIdx.x; i < 4*32*NPLANE; i += 256) {
    int w = i / (32*NPLANE);
    int rem = i - w*(32*NPLANE);
    int cc = rem >> 5;
    int q = rem & 31;
    float v = ((float*)&smem[w][0])[cc*32 + q];
    part[(pb + cc)*HW + qt*128 + w*32 + q] = (ushort)(cvtpk(v, v) & 0xffffu);
  }
}

// ---------- K3: tail — loads hoisted above SE to hide latency ----------
// 128 blocks x 768 thr (12 waves); wave w owns 4 WAVE-UNIFORM channels.
__global__ __launch_bounds__(768) void k_tail(const ushort* __restrict__ part,
                                              const float* __restrict__ x,
                                              const float* __restrict__ lw1,
                                              const float* __restrict__ lb1,
                                              const float* __restrict__ bpool,
                                              const float* __restrict__ w1,
                                              const float* __restrict__ b1,
                                              const float* __restrict__ w2,
                                              const float* __restrict__ b2,
                                              const float* __restrict__ beta,
                                              const float* __restrict__ beta2,
                                              const float* __restrict__ lw2,
                                              const float* __restrict__ lb2,
                                              const float* __restrict__ w4,
                                              const float* __restrict__ b4,
                                              const float* __restrict__ w5,
                                              const float* __restrict__ b5,
                                              const float* __restrict__ gamma,
                                              float* __restrict__ out) {
  __shared__ float sepm[CH][4];
  __shared__ float pmL[CH];
  __shared__ float yrL[4];
  __shared__ float seL[CH];
  __shared__ float r1[12][64], r2[12][64], r3[12][64], r4[12][64];
  __shared__ float xt[CH][65];   // LN2 output
  __shared__ float gt[CH][65];   // gate output
  int t = threadIdx.x;
  int px = t & 63, w = t >> 6;        // 12 waves
  int h = w >> 2;
  int c0 = __builtin_amdgcn_readfirstlane(w * 4);
  int qoff = __builtin_amdgcn_readfirstlane((w & 3) * 4);
  int gp = blockIdx.x*64 + px;
  int b = gp >> 12, n = gp & 4095;
  int bh = b*NH + h;

  // HOISTED: ksplit reduce + LN1 x-loads issued BEFORE the SE MLP so the
  // global-load latency hides under the SE's LDS/barrier phases.
  float acc[4] = {0,0,0,0};
  float den = 0.f;
#pragma unroll
  for (int ks = 0; ks < KSPLIT; ++ks) {
    const ushort* pl = part + ((size_t)((ks*6+bh)*NPLANE + qoff))*HW + n;
#pragma unroll
    for (int cc = 0; cc < 4; ++cc) acc[cc] += bf2f(pl[(size_t)cc*HW]);
    den += bf2f(pl[(size_t)(16 - qoff)*HW]);
  }
  const float* xp = x + ((size_t)b*CH + c0)*HW + n;
  float xv[4]; float s = 0.f, ssum = 0.f;
#pragma unroll
  for (int cc = 0; cc < 4; ++cc) {
    float vv = xp[(size_t)cc*HW];
    xv[cc] = vv; s += vv; ssum += vv*vv;
  }
  r1[w][px] = s; r2[w][px] = ssum;

  // SE MLP (block-redundant; bpool is L2-hot; 64 row-partials per b)
  if (t < 192) {
    int c = t % CH, j = t / CH;       // j 0..3
    const float* bp = bpool + (size_t)(b*64 + j*16)*CH + c;
    float a = 0.f;
#pragma unroll
    for (int i = 0; i < 16; ++i) a += bp[(size_t)i*CH];
    sepm[c][j] = a;
  }
  __syncthreads();
  if (t < CH) pmL[t] = (sepm[t][0]+sepm[t][1]+sepm[t][2]+sepm[t][3]) * (1.f/HW);
  __syncthreads();
  if (t < RR) {
    float a = b1[t];
    for (int c = 0; c < CH; ++c) a += w1[t*CH+c]*pmL[c];
    yrL[t] = fmaxf(a, 0.f);
  }
  __syncthreads();
  if (t < CH) {
    float a = b2[t];
    for (int r = 0; r < RR; ++r) a += w2[t*RR+r]*yrL[r];
    seL[t] = 1.f/(1.f+__expf(-a));
  }
  __syncthreads();

  float stot = 0.f, sstot = 0.f;
#pragma unroll
  for (int i = 0; i < 12; ++i) { stot += r1[i][px]; sstot += r2[i][px]; }
  float mu = stot*(1.f/CH);
  float rs = rsqrtf(sstot*(1.f/CH) - mu*mu + 1e-6f);
  float inv = 1.f / den;
  float yv[4]; float s2 = 0.f, ss2 = 0.f;
#pragma unroll
  for (int cc = 0; cc < 4; ++cc) {
    int c = c0 + cc;
    float xnv = lw1[c]*((xv[cc]-mu)*rs) + lb1[c];
    float y = xv[cc] + xnv*seL[c]*beta[c] + acc[cc]*inv*beta2[c];
    yv[cc] = y; s2 += y; ss2 += y*y;
  }
  r3[w][px] = s2; r4[w][px] = ss2;
  __syncthreads();
  float s2t = 0.f, ss2t = 0.f;
#pragma unroll
  for (int i = 0; i < 12; ++i) { s2t += r3[i][px]; ss2t += r4[i][px]; }
  float mu2 = s2t*(1.f/CH);
  float rs2 = rsqrtf(ss2t*(1.f/CH) - mu2*mu2 + 1e-6f);
#pragma unroll
  for (int cc = 0; cc < 4; ++cc) {
    int c = c0 + cc;
    xt[c][px] = lw2[c]*((yv[cc]-mu2)*rs2) + lb2[c];
  }
  __syncthreads();

  // conv4 + gate: wave-uniform rows via s_load
  float f1[4], f2[4];
#pragma unroll
  for (int j = 0; j < 4; ++j) { f1[j] = b4[c0+j]; f2[j] = b4[CH+c0+j]; }
#pragma unroll 8
  for (int c = 0; c < CH; ++c) {
    float tc = xt[c][px];
#pragma unroll
    for (int j = 0; j < 4; ++j) {
      f1[j] += w4[(size_t)(c0+j)*CH + c] * tc;
      f2[j] += w4[(size_t)(CH+c0+j)*CH + c] * tc;
    }
  }
#pragma unroll
  for (int j = 0; j < 4; ++j) gt[c0+j][px] = f1[j]*f2[j];
  __syncthreads();

  // conv5 + residual
  float f5[4];
#pragma unroll
  for (int j = 0; j < 4; ++j) f5[j] = b5[c0+j];
#pragma unroll 8
  for (int c = 0; c < CH; ++c) {
    float gc = gt[c][px];
#pragma unroll
    for (int j = 0; j < 4; ++j) f5[j] += w5[(size_t)(c0+j)*CH + c] * gc;
  }
  float* op = out + ((size_t)b*CH + c0)*HW + n;
#pragma unroll
  for (int j = 0; j < 4; ++j)
    op[(size_t)j*HW] = yv[j] + f5[j]*gamma[c0+j];
}

extern "C" void kernel_launch(void* const* d_in, const int* in_sizes, int n_in,
                              void* d_out, int out_size, void* d_ws, size_t ws_size,
                              hipStream_t stream) {
  const float* x      = (const float*)d_in[0];
  const float* ln1_w  = (const float*)d_in[1];
  const float* ln1_b  = (const float*)d_in[2];
  const float* qkv_w  = (const float*)d_in[3];
  const float* qkv_b  = (const float*)d_in[4];
  const float* dw_w   = (const float*)d_in[5];
  const float* dw_b   = (const float*)d_in[6];
  const float* temp   = (const float*)d_in[7];
  const float* ca_w1  = (const float*)d_in[8];
  const float* ca_b1  = (const float*)d_in[9];
  const float* ca_w2  = (const float*)d_in[10];
  const float* ca_b2  = (const float*)d_in[11];
  const float* beta   = (const float*)d_in[12];
  const float* beta2  = (const float*)d_in[13];
  const float* ln2_w  = (const float*)d_in[14];
  const float* ln2_b  = (const float*)d_in[15];
  const float* conv4_w= (const float*)d_in[16];
  const float* conv4_b= (const float*)d_in[17];
  const float* conv5_w= (const float*)d_in[18];
  const float* conv5_b= (const float*)d_in[19];
  const float* gamma  = (const float*)d_in[20];

  float* ws   = (float*)d_ws;
  float* bp   = ws + OFF_BP;
  ushort* Qb  = (ushort*)(ws + OFF_QB);
  ushort* Kb  = (ushort*)(ws + OFF_KB);
  ushort* Vtb = (ushort*)(ws + OFF_VT);
  ushort* part= (ushort*)(ws + OFF_PART);
  float* out  = (float*)d_out;

  k_front<<<384, 512, 0, stream>>>(x, ln1_w, ln1_b, qkv_w, qkv_b,
                                   dw_w, dw_b, temp, Qb, Kb, Vtb, bp);
  k_attn <<<768, 256, 0, stream>>>(Qb, Kb, Vtb, part);
  k_tail <<<128, 768, 0, stream>>>(part, x, ln1_w, ln1_b, bp,
                                   ca_w1, ca_b1, ca_w2, ca_b2,
                                   beta, beta2, ln2_w, ln2_b,
                                   conv4_w, conv4_b, conv5_w, conv5_b,
                                   gamma, out);
}